// Round 1
// 629.771 us; speedup vs baseline: 1.0751x; 1.0751x over previous
//
#include <hip/hip_runtime.h>
#include <math.h>
#include <stdint.h>

#define S_SEQ 256
#define T_TOK 512
#define BERT 768
#define POSD 128
#define H1 1024
#define NC 6

#define CHUNK_T 128   // tokens per block (4 blocks per sequence)
#define WTOK 32       // tokens per wave (4 waves per block)

// ---------------------------------------------------------------------------
// 64-lane wave sum, pure VALU pipe (no ds_swizzle):
// 4 x DPP row_ror adds (16-lane row sum) + permlane16/32_swap (gfx950) for
// the cross-row levels. Dependent chain ~50 cyc vs ~720 cyc for 6x ds_swizzle.
// ---------------------------------------------------------------------------
__device__ __forceinline__ float wave_sum64(float x) {
    x += __int_as_float(__builtin_amdgcn_update_dpp(
            0, __float_as_int(x), 0x128, 0xF, 0xF, true));   // row_ror:8
    x += __int_as_float(__builtin_amdgcn_update_dpp(
            0, __float_as_int(x), 0x124, 0xF, 0xF, true));   // row_ror:4
    x += __int_as_float(__builtin_amdgcn_update_dpp(
            0, __float_as_int(x), 0x122, 0xF, 0xF, true));   // row_ror:2
    x += __int_as_float(__builtin_amdgcn_update_dpp(
            0, __float_as_int(x), 0x121, 0xF, 0xF, true));   // row_ror:1
    // now every lane holds its 16-lane row sum {r0,r1,r2,r3}
    float a = x, b = x;
    asm("v_permlane16_swap_b32 %0, %1" : "+v"(a), "+v"(b));
    x = a + b;                 // all lanes: r0+r1 (rows 0/1) or r2+r3 (rows 2/3)
    a = x; b = x;
    asm("v_permlane32_swap_b32 %0, %1" : "+v"(a), "+v"(b));
    return a + b;              // all lanes: r0+r1+r2+r3
}

// ---------------------------------------------------------------------------
// Kernel 1: fused attention-logit + online-softmax weighted pooling.
// Register-resident; explicit next-iteration prefetch so the global-load
// stream never waits on the (now cheap, VALU-only) reduce/softmax chain.
// grid = 1024 (4 blocks per s), block = 256 (4 waves).
// ---------------------------------------------------------------------------
__global__ __launch_bounds__(256, 4) void pool_kernel(
    const float* __restrict__ emb, const float* __restrict__ pos,
    const float* __restrict__ Wa, const float* __restrict__ ba,
    float* __restrict__ part_acc, float* __restrict__ part_ml)
{
    __shared__ float mg[4 * BERT];   // 12 KB merge buffer
    __shared__ float wml[8];

    const int tid = threadIdx.x;
    const int w   = tid >> 6;
    const int l   = tid & 63;
    const int b   = blockIdx.x;
    const int s   = b >> 2;
    const int t0  = (b & 3) * CHUNK_T + w * WTOK;   // wave's first token

    // per-lane weights: 12 emb cols + 2 pos cols
    const float4* Wa4 = (const float4*)Wa;
    const float4 wa0 = Wa4[l];
    const float4 wa1 = Wa4[64 + l];
    const float4 wa2 = Wa4[128 + l];
    const float2 wp  = ((const float2*)(Wa + BERT))[l];
    const float  bav = ba[0];

    const float4* erow = (const float4*)(emb + ((size_t)s * T_TOK + t0) * BERT);
    const float2* prow = (const float2*)(pos + ((size_t)s * T_TOK + t0) * POSD);

    float m = -INFINITY, lsum = 0.f;
    float acc[12];
    #pragma unroll
    for (int j = 0; j < 12; ++j) acc[j] = 0.f;

    // prefetch iteration 0 (tokens 0,1)
    float4 na0 = erow[l],       na1 = erow[64 + l],  na2 = erow[128 + l];
    float4 nb0 = erow[192 + l], nb1 = erow[256 + l], nb2 = erow[320 + l];
    float2 nq0 = prow[l],       nq1 = prow[64 + l];

    for (int i = 0; i < WTOK; i += 2) {
        const float4 a0 = na0, a1 = na1, a2 = na2;
        const float4 b0 = nb0, b1 = nb1, b2 = nb2;
        const float2 q0 = nq0, q1 = nq1;

        if (i + 2 < WTOK) {   // issue next token-pair loads before the chain
            const float4* rn = erow + (size_t)(i + 2) * (BERT / 4);
            na0 = rn[l];       na1 = rn[64 + l];  na2 = rn[128 + l];
            nb0 = rn[192 + l]; nb1 = rn[256 + l]; nb2 = rn[320 + l];
            nq0 = prow[(i + 2) * (POSD / 2) + l];
            nq1 = prow[(i + 3) * (POSD / 2) + l];
        }

        float d0 = a0.x*wa0.x + a0.y*wa0.y + a0.z*wa0.z + a0.w*wa0.w
                 + a1.x*wa1.x + a1.y*wa1.y + a1.z*wa1.z + a1.w*wa1.w
                 + a2.x*wa2.x + a2.y*wa2.y + a2.z*wa2.z + a2.w*wa2.w
                 + q0.x*wp.x  + q0.y*wp.y;
        float d1 = b0.x*wa0.x + b0.y*wa0.y + b0.z*wa0.z + b0.w*wa0.w
                 + b1.x*wa1.x + b1.y*wa1.y + b1.z*wa1.z + b1.w*wa1.w
                 + b2.x*wa2.x + b2.y*wa2.y + b2.z*wa2.z + b2.w*wa2.w
                 + q1.x*wp.x  + q1.y*wp.y;

        d0 = wave_sum64(d0);
        d1 = wave_sum64(d1);

        const float lg0 = d0 + bav;
        const float lg1 = d1 + bav;
        const float mn  = fmaxf(m, fmaxf(lg0, lg1));
        const float alpha = __expf(m - mn);   // first iter: exp(-inf)=0
        const float p0 = __expf(lg0 - mn);
        const float p1 = __expf(lg1 - mn);
        lsum = lsum * alpha + p0 + p1;
        m = mn;

        acc[0]  = fmaf(p0, a0.x, fmaf(p1, b0.x, acc[0]  * alpha));
        acc[1]  = fmaf(p0, a0.y, fmaf(p1, b0.y, acc[1]  * alpha));
        acc[2]  = fmaf(p0, a0.z, fmaf(p1, b0.z, acc[2]  * alpha));
        acc[3]  = fmaf(p0, a0.w, fmaf(p1, b0.w, acc[3]  * alpha));
        acc[4]  = fmaf(p0, a1.x, fmaf(p1, b1.x, acc[4]  * alpha));
        acc[5]  = fmaf(p0, a1.y, fmaf(p1, b1.y, acc[5]  * alpha));
        acc[6]  = fmaf(p0, a1.z, fmaf(p1, b1.z, acc[6]  * alpha));
        acc[7]  = fmaf(p0, a1.w, fmaf(p1, b1.w, acc[7]  * alpha));
        acc[8]  = fmaf(p0, a2.x, fmaf(p1, b2.x, acc[8]  * alpha));
        acc[9]  = fmaf(p0, a2.y, fmaf(p1, b2.y, acc[9]  * alpha));
        acc[10] = fmaf(p0, a2.z, fmaf(p1, b2.z, acc[10] * alpha));
        acc[11] = fmaf(p0, a2.w, fmaf(p1, b2.w, acc[11] * alpha));
    }

    // --- in-block merge of the 4 per-wave partials (by absolute column) ---
    #pragma unroll
    for (int j = 0; j < 4; ++j) {
        mg[w * BERT +       l * 4 + j] = acc[j];
        mg[w * BERT + 256 + l * 4 + j] = acc[4 + j];
        mg[w * BERT + 512 + l * 4 + j] = acc[8 + j];
    }
    if (l == 0) { wml[w * 2] = m; wml[w * 2 + 1] = lsum; }
    __syncthreads();

    const float m0 = wml[0], l0 = wml[1], m1 = wml[2], l1 = wml[3];
    const float m2 = wml[4], l2 = wml[5], m3 = wml[6], l3 = wml[7];
    const float M  = fmaxf(fmaxf(m0, m1), fmaxf(m2, m3));
    const float e0 = __expf(m0 - M), e1 = __expf(m1 - M);
    const float e2 = __expf(m2 - M), e3 = __expf(m3 - M);
    const float lt = l0 * e0 + l1 * e1 + l2 * e2 + l3 * e3;
    #pragma unroll
    for (int k = 0; k < 3; ++k) {
        const int col = tid * 3 + k;
        part_acc[(size_t)b * BERT + col] =
              e0 * mg[col] + e1 * mg[BERT + col]
            + e2 * mg[2 * BERT + col] + e3 * mg[3 * BERT + col];
    }
    if (tid == 0) { part_ml[b * 2] = M; part_ml[b * 2 + 1] = lt; }
}

// ---------------------------------------------------------------------------
// Kernel 2: merge the 4 partials per sequence, normalize, segment-sum.
// Also seeds the MLP pre-activation accumulators h1/h2 with their biases
// (so the K-split mlp_layer_part kernels can atomicAdd partial sums).
// grid = 64, block = 256 (3 cols per thread).
// ---------------------------------------------------------------------------
__global__ void combine_segsum(
    const float* __restrict__ part_acc, const float* __restrict__ part_ml,
    const int* __restrict__ seg, float* __restrict__ vecs,
    const float* __restrict__ b1, const float* __restrict__ b2,
    float* __restrict__ h1, float* __restrict__ h2)
{
    const int c = blockIdx.x;
    const int tid = threadIdx.x;

    // bias-seed the MLP accumulators for this comment
    for (int j = tid; j < H1; j += 256) {
        h1[(size_t)c * H1 + j] = b1[j];
        h2[(size_t)c * H1 + j] = b2[j];
    }

    float v0 = 0.f, v1 = 0.f, v2 = 0.f;
    for (int s = 0; s < S_SEQ; ++s) {
        if (seg[s] != c) continue;
        const int p = s * 4;
        const float m0 = part_ml[(p+0)*2], l0 = part_ml[(p+0)*2+1];
        const float m1 = part_ml[(p+1)*2], l1 = part_ml[(p+1)*2+1];
        const float m2 = part_ml[(p+2)*2], l2 = part_ml[(p+2)*2+1];
        const float m3 = part_ml[(p+3)*2], l3 = part_ml[(p+3)*2+1];
        const float M  = fmaxf(fmaxf(m0, m1), fmaxf(m2, m3));
        const float e0 = __expf(m0 - M), e1 = __expf(m1 - M);
        const float e2 = __expf(m2 - M), e3 = __expf(m3 - M);
        const float inv = 1.0f / (l0*e0 + l1*e1 + l2*e2 + l3*e3);
        const int col = tid * 3;
        v0 += inv * (e0 * part_acc[(size_t)(p+0)*BERT + col]
                   + e1 * part_acc[(size_t)(p+1)*BERT + col]
                   + e2 * part_acc[(size_t)(p+2)*BERT + col]
                   + e3 * part_acc[(size_t)(p+3)*BERT + col]);
        v1 += inv * (e0 * part_acc[(size_t)(p+0)*BERT + col + 1]
                   + e1 * part_acc[(size_t)(p+1)*BERT + col + 1]
                   + e2 * part_acc[(size_t)(p+2)*BERT + col + 1]
                   + e3 * part_acc[(size_t)(p+3)*BERT + col + 1]);
        v2 += inv * (e0 * part_acc[(size_t)(p+0)*BERT + col + 2]
                   + e1 * part_acc[(size_t)(p+1)*BERT + col + 2]
                   + e2 * part_acc[(size_t)(p+2)*BERT + col + 2]
                   + e3 * part_acc[(size_t)(p+3)*BERT + col + 2]);
    }
    vecs[(size_t)c*BERT + tid*3 + 0] = v0;
    vecs[(size_t)c*BERT + tid*3 + 1] = v1;
    vecs[(size_t)c*BERT + tid*3 + 2] = v2;
}

// ---------------------------------------------------------------------------
// Kernel 3/4: K-split partial dense layer. out (pre-seeded with bias) +=
// in-slice @ W-slice via atomicAdd. LeakyReLU is applied by the CONSUMER on
// load (lr_in selects it for this kernel's own input).
// grid = dim3(4, 64, 4) = 1024 blocks -> 4 blocks/CU, 16 waves/CU (vs 4
// before): latency-bound inner loop now has 4x the TLP to hide L2 hits.
// ---------------------------------------------------------------------------
__global__ __launch_bounds__(256) void mlp_layer_part(
    const float* __restrict__ in, const float* __restrict__ W,
    float* __restrict__ out, int K, int lr_in)
{
    __shared__ float v[256];             // this block's K-chunk of the input row
    const int c      = blockIdx.y;
    const int kchunk = K >> 2;           // 192 (K=768) or 256 (K=1024)
    const int k0     = blockIdx.z * kchunk;
    const int tid    = threadIdx.x;
    const int j      = blockIdx.x * 256 + tid;

    if (tid < kchunk) {
        float x = in[(size_t)c * K + k0 + tid];
        if (lr_in) x = x > 0.f ? x : 0.01f * x;
        v[tid] = x;
    }
    __syncthreads();

    float a0 = 0.f, a1 = 0.f, a2 = 0.f, a3 = 0.f;
    const float* Wp = W + (size_t)k0 * H1 + j;
    #pragma unroll 4
    for (int k = 0; k < kchunk; k += 4) {
        a0 = fmaf(v[k    ], Wp[(size_t)(k    ) * H1], a0);
        a1 = fmaf(v[k + 1], Wp[(size_t)(k + 1) * H1], a1);
        a2 = fmaf(v[k + 2], Wp[(size_t)(k + 2) * H1], a2);
        a3 = fmaf(v[k + 3], Wp[(size_t)(k + 3) * H1], a3);
    }
    atomicAdd(&out[(size_t)c * H1 + j], (a0 + a1) + (a2 + a3));
}

// ---------------------------------------------------------------------------
// Kernel 5: out = sigmoid(leaky_relu(h2_pre) @ W3 + b3). grid = 64, block 256.
// ---------------------------------------------------------------------------
__global__ void mlp_out(
    const float* __restrict__ h, const float* __restrict__ W3,
    const float* __restrict__ b3, float* __restrict__ out)
{
    __shared__ float v[H1];
    __shared__ float red[NC][4];
    const int c = blockIdx.x;
    const int tid = threadIdx.x;
    const int wave = tid >> 6, lane = tid & 63;
    for (int i = tid; i < H1; i += 256) {
        float x = h[(size_t)c * H1 + i];
        v[i] = x > 0.f ? x : 0.01f * x;   // h2 is stored pre-activation now
    }
    __syncthreads();
    float po[NC] = {0.f, 0.f, 0.f, 0.f, 0.f, 0.f};
    for (int k = tid; k < H1; k += 256) {
        const float hv = v[k];
        #pragma unroll
        for (int o = 0; o < NC; ++o) po[o] = fmaf(hv, W3[k * NC + o], po[o]);
    }
    #pragma unroll
    for (int o = 0; o < NC; ++o) {
        float d = po[o];
        #pragma unroll
        for (int off = 32; off >= 1; off >>= 1) d += __shfl_xor(d, off, 64);
        if (lane == 0) red[o][wave] = d;
    }
    __syncthreads();
    if (tid < NC) {
        const float sum = red[tid][0] + red[tid][1] + red[tid][2] + red[tid][3] + b3[tid];
        out[c * NC + tid] = 1.0f / (1.0f + __expf(-sum));
    }
}

// ---------------------------------------------------------------------------
extern "C" void kernel_launch(void* const* d_in, const int* in_sizes, int n_in,
                              void* d_out, int out_size, void* d_ws, size_t ws_size,
                              hipStream_t stream)
{
    const float* emb = (const float*)d_in[0];
    const float* pos = (const float*)d_in[1];
    const float* Wa  = (const float*)d_in[2];
    const float* ba  = (const float*)d_in[3];
    const float* W1  = (const float*)d_in[4];
    const float* b1  = (const float*)d_in[5];
    const float* W2  = (const float*)d_in[6];
    const float* b2  = (const float*)d_in[7];
    const float* W3  = (const float*)d_in[8];
    const float* b3  = (const float*)d_in[9];
    const int*   seg = (const int*)d_in[10];
    float* out = (float*)d_out;

    float* ws = (float*)d_ws;
    float* part_acc = ws;                        // 1024*768
    float* part_ml  = part_acc + 1024 * BERT;    // 1024*2
    float* vecs     = part_ml  + 1024 * 2;       // 64*768
    float* h1       = vecs     + 64 * BERT;      // 64*1024 (pre-activation)
    float* h2       = h1       + 64 * H1;        // 64*1024 (pre-activation)

    pool_kernel<<<1024, 256, 0, stream>>>(emb, pos, Wa, ba, part_acc, part_ml);
    combine_segsum<<<64, 256, 0, stream>>>(part_acc, part_ml, seg, vecs,
                                           b1, b2, h1, h2);
    mlp_layer_part<<<dim3(4, 64, 4), 256, 0, stream>>>(vecs, W1, h1, BERT, 0);
    mlp_layer_part<<<dim3(4, 64, 4), 256, 0, stream>>>(h1, W2, h2, H1, 1);
    mlp_out<<<64, 256, 0, stream>>>(h2, W3, b3, out);
}